// Round 1
// baseline (267.731 us; speedup 1.0000x reference)
//
#include <hip/hip_runtime.h>
#include <math.h>

// Spherical harmonics edge attributes, lmax=2.
// Outputs (concat flat): edge_vec [E,3] | edge_length [E] | edge_sh [E,9]

#define SQRT3 1.7320508075688772f
#define SQRT5 2.2360679774997896f

__global__ __launch_bounds__(256) void sh_edge_kernel(
    const float* __restrict__ pos,        // [N,3]
    const int*   __restrict__ edge_index, // [2,E]
    const float* __restrict__ shift,      // [E,3]
    float* __restrict__ out_vec,          // [E,3]
    float* __restrict__ out_len,          // [E]
    float* __restrict__ out_sh,           // [E,9]
    int n_edges)
{
    const int t  = blockIdx.x * blockDim.x + threadIdx.x;
    const int e0 = t * 4;
    if (e0 >= n_edges) return;

    float vx[4], vy[4], vz[4], len[4];
    float ux[4], uy[4], uz[4];

    if (e0 + 3 < n_edges) {
        // ---- fully vectorized path (4 edges) ----
        const int4 src4 = *reinterpret_cast<const int4*>(edge_index + e0);
        const int4 dst4 = *reinterpret_cast<const int4*>(edge_index + n_edges + e0);
        const float4* sb = reinterpret_cast<const float4*>(shift + 3 * (size_t)e0);
        float4 s0 = sb[0], s1 = sb[1], s2 = sb[2];

        const int srcs[4] = {src4.x, src4.y, src4.z, src4.w};
        const int dsts[4] = {dst4.x, dst4.y, dst4.z, dst4.w};
        const float sx[4] = {s0.x, s0.w, s1.z, s2.y};
        const float sy[4] = {s0.y, s1.x, s1.w, s2.z};
        const float sz[4] = {s0.z, s1.y, s2.x, s2.w};

        #pragma unroll
        for (int i = 0; i < 4; ++i) {
            const float* ps = pos + 3 * (size_t)srcs[i];
            const float* pd = pos + 3 * (size_t)dsts[i];
            float x = pd[0] - ps[0] - sx[i];
            float y = pd[1] - ps[1] - sy[i];
            float z = pd[2] - ps[2] - sz[i];
            vx[i] = x; vy[i] = y; vz[i] = z;
            float sq = x * x + y * y + z * z;
            float r  = rsqrtf(sq);
            len[i]   = sq * r;          // == sqrt(sq)
            ux[i] = x * r; uy[i] = y * r; uz[i] = z * r;
        }

        // ---- edge_vec: 12 contiguous floats ----
        float4* ov = reinterpret_cast<float4*>(out_vec + 3 * (size_t)e0);
        ov[0] = make_float4(vx[0], vy[0], vz[0], vx[1]);
        ov[1] = make_float4(vy[1], vz[1], vx[2], vy[2]);
        ov[2] = make_float4(vz[2], vx[3], vy[3], vz[3]);

        // ---- edge_length: 4 contiguous floats ----
        *reinterpret_cast<float4*>(out_len + e0) =
            make_float4(len[0], len[1], len[2], len[3]);

        // ---- edge_sh: 36 contiguous floats ----
        float shb[36];
        #pragma unroll
        for (int i = 0; i < 4; ++i) {
            float x = ux[i], y = uy[i], z = uz[i];
            float x2 = x * x, y2 = y * y, z2 = z * z;
            float* o = shb + 9 * i;
            o[0] = 1.0f;
            o[1] = SQRT3 * x;
            o[2] = SQRT3 * y;
            o[3] = SQRT3 * z;
            o[4] = SQRT5 * SQRT3 * x * z;
            o[5] = SQRT5 * SQRT3 * x * y;
            o[6] = SQRT5 * (y2 - 0.5f * (x2 + z2));
            o[7] = SQRT5 * SQRT3 * y * z;
            o[8] = SQRT5 * 0.5f * SQRT3 * (z2 - x2);
        }
        float4* os = reinterpret_cast<float4*>(out_sh + 9 * (size_t)e0);
        #pragma unroll
        for (int j = 0; j < 9; ++j) {
            os[j] = make_float4(shb[4 * j + 0], shb[4 * j + 1],
                                shb[4 * j + 2], shb[4 * j + 3]);
        }
    } else {
        // ---- scalar tail ----
        for (int e = e0; e < n_edges; ++e) {
            int s = edge_index[e];
            int d = edge_index[n_edges + e];
            float x = pos[3 * (size_t)d + 0] - pos[3 * (size_t)s + 0] - shift[3 * (size_t)e + 0];
            float y = pos[3 * (size_t)d + 1] - pos[3 * (size_t)s + 1] - shift[3 * (size_t)e + 1];
            float z = pos[3 * (size_t)d + 2] - pos[3 * (size_t)s + 2] - shift[3 * (size_t)e + 2];
            out_vec[3 * (size_t)e + 0] = x;
            out_vec[3 * (size_t)e + 1] = y;
            out_vec[3 * (size_t)e + 2] = z;
            float sq = x * x + y * y + z * z;
            float r  = rsqrtf(sq);
            out_len[e] = sq * r;
            float nx = x * r, ny = y * r, nz = z * r;
            float x2 = nx * nx, y2 = ny * ny, z2 = nz * nz;
            float* o = out_sh + 9 * (size_t)e;
            o[0] = 1.0f;
            o[1] = SQRT3 * nx;
            o[2] = SQRT3 * ny;
            o[3] = SQRT3 * nz;
            o[4] = SQRT5 * SQRT3 * nx * nz;
            o[5] = SQRT5 * SQRT3 * nx * ny;
            o[6] = SQRT5 * (y2 - 0.5f * (x2 + z2));
            o[7] = SQRT5 * SQRT3 * ny * nz;
            o[8] = SQRT5 * 0.5f * SQRT3 * (z2 - x2);
        }
    }
}

extern "C" void kernel_launch(void* const* d_in, const int* in_sizes, int n_in,
                              void* d_out, int out_size, void* d_ws, size_t ws_size,
                              hipStream_t stream) {
    const float* pos        = (const float*)d_in[0];
    const int*   edge_index = (const int*)d_in[1];
    const float* shift      = (const float*)d_in[2];

    const int n_edges = in_sizes[2] / 3;   // shift is [E,3]

    float* out_vec = (float*)d_out;                      // [E,3]
    float* out_len = (float*)d_out + 3 * (size_t)n_edges; // [E]
    float* out_sh  = (float*)d_out + 4 * (size_t)n_edges; // [E,9]

    const int threads  = 256;
    const int n_thr    = (n_edges + 3) / 4;
    const int blocks   = (n_thr + threads - 1) / threads;

    sh_edge_kernel<<<blocks, threads, 0, stream>>>(
        pos, edge_index, shift, out_vec, out_len, out_sh, n_edges);
}

// Round 2
// 239.244 us; speedup vs baseline: 1.1191x; 1.1191x over previous
//
#include <hip/hip_runtime.h>
#include <math.h>

// Spherical harmonics edge attributes, lmax=2.
// Outputs (concat flat): edge_vec [E,3] | edge_length [E] | edge_sh [E,9]
//
// Strategy: 1 edge/thread, 256 threads/block.
//  - pos packed to float4 in d_ws by a prep kernel -> gathers are 1x dwordx4
//  - shift staged through LDS with coalesced float4 loads
//  - all outputs staged in LDS, flushed with coalesced float4 stores

#define SQRT3 1.7320508075688772f
#define SQRT5 2.2360679774997896f

__global__ __launch_bounds__(256) void pack_pos4(
    const float* __restrict__ pos, float4* __restrict__ pos4, int n)
{
    int i = blockIdx.x * blockDim.x + threadIdx.x;
    if (i < n) {
        pos4[i] = make_float4(pos[3 * (size_t)i + 0],
                              pos[3 * (size_t)i + 1],
                              pos[3 * (size_t)i + 2], 0.0f);
    }
}

__global__ __launch_bounds__(256) void sh_edge_kernel(
    const float4* __restrict__ pos4,      // [N] packed (may be null)
    const float*  __restrict__ pos,       // [N,3] fallback
    const int*    __restrict__ edge_index,// [2,E]
    const float*  __restrict__ shift,     // [E,3]
    float* __restrict__ out_vec,          // [E,3]
    float* __restrict__ out_len,          // [E]
    float* __restrict__ out_sh,           // [E,9]
    int n_edges)
{
    __shared__ float s_shift[768];   // 256 edges x 3
    __shared__ float s_vec[768];     // 256 x 3
    __shared__ float s_len[256];     // 256
    __shared__ float s_sh[2304];     // 256 x 9

    const int tid  = threadIdx.x;
    const int base = blockIdx.x * 256;
    const int nblk = min(256, n_edges - base);   // edges in this block
    const bool full = (nblk == 256);

    // ---- stage shift (coalesced) ----
    if (full) {
        const float4* g = reinterpret_cast<const float4*>(shift + 3 * (size_t)base);
        if (tid < 192) reinterpret_cast<float4*>(s_shift)[tid] = g[tid];
    } else {
        for (int i = tid; i < 3 * nblk; i += 256)
            s_shift[i] = shift[3 * (size_t)base + i];
    }
    __syncthreads();

    // ---- compute ----
    if (tid < nblk) {
        const int e = base + tid;
        const int s = edge_index[e];
        const int d = edge_index[n_edges + e];

        float psx, psy, psz, pdx, pdy, pdz;
        if (pos4) {
            float4 ps = pos4[s];
            float4 pd = pos4[d];
            psx = ps.x; psy = ps.y; psz = ps.z;
            pdx = pd.x; pdy = pd.y; pdz = pd.z;
        } else {
            psx = pos[3 * (size_t)s + 0]; psy = pos[3 * (size_t)s + 1]; psz = pos[3 * (size_t)s + 2];
            pdx = pos[3 * (size_t)d + 0]; pdy = pos[3 * (size_t)d + 1]; pdz = pos[3 * (size_t)d + 2];
        }

        float x = pdx - psx - s_shift[3 * tid + 0];
        float y = pdy - psy - s_shift[3 * tid + 1];
        float z = pdz - psz - s_shift[3 * tid + 2];

        s_vec[3 * tid + 0] = x;
        s_vec[3 * tid + 1] = y;
        s_vec[3 * tid + 2] = z;

        float sq = x * x + y * y + z * z;
        float r  = rsqrtf(sq);
        s_len[tid] = sq * r;            // sqrt(sq)

        float nx = x * r, ny = y * r, nz = z * r;
        float x2 = nx * nx, y2 = ny * ny, z2 = nz * nz;

        float* o = s_sh + 9 * tid;
        o[0] = 1.0f;
        o[1] = SQRT3 * nx;
        o[2] = SQRT3 * ny;
        o[3] = SQRT3 * nz;
        o[4] = SQRT5 * SQRT3 * nx * nz;
        o[5] = SQRT5 * SQRT3 * nx * ny;
        o[6] = SQRT5 * (y2 - 0.5f * (x2 + z2));
        o[7] = SQRT5 * SQRT3 * ny * nz;
        o[8] = SQRT5 * 0.5f * SQRT3 * (z2 - x2);
    }
    __syncthreads();

    // ---- flush outputs (coalesced float4) ----
    if (full) {
        float4* gv = reinterpret_cast<float4*>(out_vec + 3 * (size_t)base);
        const float4* lv = reinterpret_cast<const float4*>(s_vec);
        if (tid < 192) gv[tid] = lv[tid];

        float4* gl = reinterpret_cast<float4*>(out_len + (size_t)base);
        const float4* ll = reinterpret_cast<const float4*>(s_len);
        if (tid < 64) gl[tid] = ll[tid];

        float4* gs = reinterpret_cast<float4*>(out_sh + 9 * (size_t)base);
        const float4* ls = reinterpret_cast<const float4*>(s_sh);
        gs[tid]       = ls[tid];
        gs[256 + tid] = ls[256 + tid];
        if (tid < 64) gs[512 + tid] = ls[512 + tid];
    } else {
        for (int i = tid; i < 3 * nblk; i += 256) out_vec[3 * (size_t)base + i] = s_vec[i];
        for (int i = tid; i < nblk;     i += 256) out_len[(size_t)base + i]     = s_len[i];
        for (int i = tid; i < 9 * nblk; i += 256) out_sh[9 * (size_t)base + i]  = s_sh[i];
    }
}

extern "C" void kernel_launch(void* const* d_in, const int* in_sizes, int n_in,
                              void* d_out, int out_size, void* d_ws, size_t ws_size,
                              hipStream_t stream) {
    const float* pos        = (const float*)d_in[0];
    const int*   edge_index = (const int*)d_in[1];
    const float* shift      = (const float*)d_in[2];

    const int n_nodes = in_sizes[0] / 3;   // pos is [N,3]
    const int n_edges = in_sizes[2] / 3;   // shift is [E,3]

    float* out_vec = (float*)d_out;                        // [E,3]
    float* out_len = (float*)d_out + 3 * (size_t)n_edges;  // [E]
    float* out_sh  = (float*)d_out + 4 * (size_t)n_edges;  // [E,9]

    float4* pos4 = nullptr;
    if (ws_size >= (size_t)n_nodes * sizeof(float4)) {
        pos4 = (float4*)d_ws;
        int blocks = (n_nodes + 255) / 256;
        pack_pos4<<<blocks, 256, 0, stream>>>(pos, pos4, n_nodes);
    }

    const int blocks = (n_edges + 255) / 256;
    sh_edge_kernel<<<blocks, 256, 0, stream>>>(
        pos4, pos, edge_index, shift, out_vec, out_len, out_sh, n_edges);
}

// Round 4
// 236.668 us; speedup vs baseline: 1.1313x; 1.0109x over previous
//
#include <hip/hip_runtime.h>
#include <math.h>

// Spherical harmonics edge attributes, lmax=2.
// Outputs (concat flat): edge_vec [E,3] | edge_length [E] | edge_sh [E,9]
//
// Strategy: 1 edge/thread, 256 threads/block.
//  - pos packed to float4 in d_ws -> each gather is one dwordx4 (L2-resident)
//  - shift staged through LDS with coalesced non-temporal float4 loads
//  - outputs staged in LDS, flushed with coalesced NON-TEMPORAL float4 stores
//    (nt keeps the streaming traffic from evicting pos4 out of L2)
//
// Note: __builtin_nontemporal_* requires native vector types, not HIP's
// float4 class -> use ext_vector_type(4) float (v4f) for those accesses.

#define SQRT3 1.7320508075688772f
#define SQRT5 2.2360679774997896f

typedef float v4f __attribute__((ext_vector_type(4)));

__global__ __launch_bounds__(256) void pack_pos4(
    const float* __restrict__ pos, float4* __restrict__ pos4, int n)
{
    int i = blockIdx.x * blockDim.x + threadIdx.x;
    if (i < n) {
        pos4[i] = make_float4(pos[3 * (size_t)i + 0],
                              pos[3 * (size_t)i + 1],
                              pos[3 * (size_t)i + 2], 0.0f);
    }
}

__global__ __launch_bounds__(256) void sh_edge_kernel(
    const float4* __restrict__ pos4,      // [N] packed (may be null)
    const float*  __restrict__ pos,       // [N,3] fallback
    const int*    __restrict__ edge_index,// [2,E]
    const float*  __restrict__ shift,     // [E,3]
    float* __restrict__ out_vec,          // [E,3]
    float* __restrict__ out_len,          // [E]
    float* __restrict__ out_sh,           // [E,9]
    int n_edges)
{
    __shared__ float s_shift[768];   // 256 edges x 3
    __shared__ float s_vec[768];     // 256 x 3
    __shared__ float s_len[256];     // 256
    __shared__ float s_sh[2304];     // 256 x 9

    const int tid  = threadIdx.x;
    const int base = blockIdx.x * 256;
    const int nblk = min(256, n_edges - base);   // edges in this block
    const bool full = (nblk == 256);

    // ---- stage shift (coalesced, non-temporal: single-use stream) ----
    if (full) {
        const v4f* g = reinterpret_cast<const v4f*>(shift + 3 * (size_t)base);
        if (tid < 192) {
            v4f v = __builtin_nontemporal_load(&g[tid]);
            reinterpret_cast<v4f*>(s_shift)[tid] = v;
        }
    } else {
        for (int i = tid; i < 3 * nblk; i += 256)
            s_shift[i] = shift[3 * (size_t)base + i];
    }
    __syncthreads();

    // ---- compute ----
    if (tid < nblk) {
        const int e = base + tid;
        const int s = __builtin_nontemporal_load(&edge_index[e]);
        const int d = __builtin_nontemporal_load(&edge_index[n_edges + e]);

        float psx, psy, psz, pdx, pdy, pdz;
        if (pos4) {
            float4 ps = pos4[s];   // cached: keep in L2
            float4 pd = pos4[d];
            psx = ps.x; psy = ps.y; psz = ps.z;
            pdx = pd.x; pdy = pd.y; pdz = pd.z;
        } else {
            psx = pos[3 * (size_t)s + 0]; psy = pos[3 * (size_t)s + 1]; psz = pos[3 * (size_t)s + 2];
            pdx = pos[3 * (size_t)d + 0]; pdy = pos[3 * (size_t)d + 1]; pdz = pos[3 * (size_t)d + 2];
        }

        float x = pdx - psx - s_shift[3 * tid + 0];
        float y = pdy - psy - s_shift[3 * tid + 1];
        float z = pdz - psz - s_shift[3 * tid + 2];

        s_vec[3 * tid + 0] = x;
        s_vec[3 * tid + 1] = y;
        s_vec[3 * tid + 2] = z;

        float sq = x * x + y * y + z * z;
        float r  = rsqrtf(sq);
        s_len[tid] = sq * r;            // sqrt(sq)

        float nx = x * r, ny = y * r, nz = z * r;
        float x2 = nx * nx, y2 = ny * ny, z2 = nz * nz;

        float* o = s_sh + 9 * tid;
        o[0] = 1.0f;
        o[1] = SQRT3 * nx;
        o[2] = SQRT3 * ny;
        o[3] = SQRT3 * nz;
        o[4] = SQRT5 * SQRT3 * nx * nz;
        o[5] = SQRT5 * SQRT3 * nx * ny;
        o[6] = SQRT5 * (y2 - 0.5f * (x2 + z2));
        o[7] = SQRT5 * SQRT3 * ny * nz;
        o[8] = SQRT5 * 0.5f * SQRT3 * (z2 - x2);
    }
    __syncthreads();

    // ---- flush outputs (coalesced non-temporal float4) ----
    if (full) {
        v4f* gv = reinterpret_cast<v4f*>(out_vec + 3 * (size_t)base);
        const v4f* lv = reinterpret_cast<const v4f*>(s_vec);
        if (tid < 192) __builtin_nontemporal_store(lv[tid], &gv[tid]);

        v4f* gl = reinterpret_cast<v4f*>(out_len + (size_t)base);
        const v4f* ll = reinterpret_cast<const v4f*>(s_len);
        if (tid < 64) __builtin_nontemporal_store(ll[tid], &gl[tid]);

        v4f* gs = reinterpret_cast<v4f*>(out_sh + 9 * (size_t)base);
        const v4f* ls = reinterpret_cast<const v4f*>(s_sh);
        __builtin_nontemporal_store(ls[tid],       &gs[tid]);
        __builtin_nontemporal_store(ls[256 + tid], &gs[256 + tid]);
        if (tid < 64) __builtin_nontemporal_store(ls[512 + tid], &gs[512 + tid]);
    } else {
        for (int i = tid; i < 3 * nblk; i += 256) out_vec[3 * (size_t)base + i] = s_vec[i];
        for (int i = tid; i < nblk;     i += 256) out_len[(size_t)base + i]     = s_len[i];
        for (int i = tid; i < 9 * nblk; i += 256) out_sh[9 * (size_t)base + i]  = s_sh[i];
    }
}

extern "C" void kernel_launch(void* const* d_in, const int* in_sizes, int n_in,
                              void* d_out, int out_size, void* d_ws, size_t ws_size,
                              hipStream_t stream) {
    const float* pos        = (const float*)d_in[0];
    const int*   edge_index = (const int*)d_in[1];
    const float* shift      = (const float*)d_in[2];

    const int n_nodes = in_sizes[0] / 3;   // pos is [N,3]
    const int n_edges = in_sizes[2] / 3;   // shift is [E,3]

    float* out_vec = (float*)d_out;                        // [E,3]
    float* out_len = (float*)d_out + 3 * (size_t)n_edges;  // [E]
    float* out_sh  = (float*)d_out + 4 * (size_t)n_edges;  // [E,9]

    float4* pos4 = nullptr;
    if (ws_size >= (size_t)n_nodes * sizeof(float4)) {
        pos4 = (float4*)d_ws;
        int pblocks = (n_nodes + 255) / 256;
        pack_pos4<<<pblocks, 256, 0, stream>>>(pos, pos4, n_nodes);
    }

    const int blocks = (n_edges + 255) / 256;
    sh_edge_kernel<<<blocks, 256, 0, stream>>>(
        pos4, pos, edge_index, shift, out_vec, out_len, out_sh, n_edges);
}